// Round 24
// baseline (167.311 us; speedup 1.0000x reference)
//
#include <hip/hip_runtime.h>
#include <hip/hip_bf16.h>

typedef _Float16 f16;
typedef f16  f16x4 __attribute__((ext_vector_type(4)));
typedef f16  f16x8 __attribute__((ext_vector_type(8)));
typedef float f32x4 __attribute__((ext_vector_type(4)));
typedef float f32x16 __attribute__((ext_vector_type(16)));

// ---------------- workspace layout ----------------
// Tpre : [256][26(c,i)][196p][8g] f16
// Wb2  : [13cg][13ky][13kx][64l][8] f16
// Wf1b : [33ks][26kstep][6nt][64l][8] f16
// Wb1  : [39q][64l][8] f16
// h2f  : [256][1029] f32
// P3   : [33][256][89] f32
static constexpr size_t TP_OFF = 0;
static constexpr size_t TP_BYTES = (size_t)256 * 26 * 196 * 8 * 2;        // 20,873,216
static constexpr size_t WB_OFF = TP_OFF + TP_BYTES;
static constexpr size_t WB_BYTES = (size_t)2197 * 64 * 8 * 2;             // 2,249,728
static constexpr size_t WF_OFF = WB_OFF + WB_BYTES;
static constexpr size_t WF_BYTES = (size_t)33 * 26 * 6 * 64 * 8 * 2;      // 5,271,552
static constexpr size_t W1_OFF = WF_OFF + WF_BYTES;
static constexpr size_t W1_BYTES = (size_t)39 * 64 * 8 * 2;               // 39,936
static constexpr size_t H2_OFF = W1_OFF + ((W1_BYTES + 255) & ~size_t(255));
static constexpr size_t H2_BYTES = (size_t)256 * 1029 * 4;                // 1,053,696
static constexpr size_t P3_OFF = H2_OFF + H2_BYTES;

static constexpr int NCH = 33;

// ------------------------------------------------------------------
// K0: prep_w1 standalone (tiny) — precedes k_mega's conv1m blocks.
// ------------------------------------------------------------------
__global__ __launch_bounds__(256) void k_prep_w1(const float* __restrict__ w1,
                                                 f16* __restrict__ Wb1) {
    int idx = blockIdx.x * 256 + threadIdx.x;
    if (idx >= 39 * 64) return;
    int l = idx & 63; int q = idx >> 6;
    int pass = q / 13, kc = q % 13;
    int o = l & 15;
    f16x8 v;
#pragma unroll
    for (int i = 0; i < 8; ++i) {
        int kk = (l >> 4) * 8 + i;
        int tap = 2 * kc + (kk >> 4);
        int j = kk & 15;
        f16 out = (f16)0;
        if (tap < 25 && j < 10 && o < 13) {
            int c = j / 5, g = j % 5;
            int ky = tap / 5, kx = tap - 5 * ky;
            float wv = w1[c * 1625 + o * 125 + ky * 25 + kx * 5 + g];
            f16 hi = (f16)wv;
            out = (pass == 2) ? (f16)(wv - (float)hi) : hi;
        }
        v[i] = out;
    }
    *(f16x8*)&Wb1[(size_t)idx * 8] = v;
}

// ------------------------------------------------------------------
// Mega-kernel bodies: conv1m (512) + prep_wb (553) + prep_wf (132).
// ------------------------------------------------------------------
__device__ __forceinline__ void prep_wb_body(const float* __restrict__ w2,
                                             f16* __restrict__ Wb2, int bid) {
    int idx = bid * 256 + threadIdx.x;   // 2197*64 = 140,608
    if (idx >= 2197 * 64) return;
    int l = idx & 63; int frag = idx >> 6;
    int kx = frag % 13; int t2 = frag / 13;
    int ky = t2 % 13; int cg = t2 / 13;
    int o = l & 31;
    f16x8 v;
    int ch0 = cg * 16 + (l >> 5) * 8;
    int rr0 = ch0 % 104;
    if (o >= 21) {
        f16x8 z = {};
        v = z;
    } else if (rr0 <= 96) {
        int c2 = ch0 / 104, ii = rr0 >> 3;
        const float* src = &w2[(size_t)(c2 * 21 + o) * 17576 + ii * 1352 + ky * 104 + kx * 8];
        float4 a0 = *(const float4*)src;
        float4 a1 = *(const float4*)(src + 4);
        v[0] = (f16)a0.x; v[1] = (f16)a0.y; v[2] = (f16)a0.z; v[3] = (f16)a0.w;
        v[4] = (f16)a1.x; v[5] = (f16)a1.y; v[6] = (f16)a1.z; v[7] = (f16)a1.w;
    } else {
#pragma unroll
        for (int i = 0; i < 8; ++i) {
            int ch = ch0 + i;
            int c2 = ch / 104, rr = ch % 104, ii = rr >> 3, gg = rr & 7;
            v[i] = (f16)w2[(size_t)(c2 * 21 + o) * 17576 + ii * 1352 + ky * 104 + kx * 8 + gg];
        }
    }
    *(f16x8*)&Wb2[(size_t)idx * 8] = v;
}

__device__ __forceinline__ void prep_wf_body(char* smem,
                                             const float* __restrict__ wf1,
                                             f16* __restrict__ Wf1b, int sub) {
    f16 (*Wl)[48 * 32] = (f16(*)[48 * 32])smem;   // [13][1536] = 39,936 B
    int oseg = sub & 1, c = (sub >> 1) & 1, ks = sub >> 2;
    int o0 = oseg * 48;
    int tid = threadIdx.x;
    for (int e = tid; e < 48 * 32; e += 256) {
        int orel = e >> 5, dl = e & 31;
        int o = o0 + orel, d = ks * 32 + dl;
        if (o < 89 && d < 1029) {
            const float* p = wf1 + ((size_t)(c * 89 + o) * 1029 + d) * 13;
            float4 q0 = *(const float4*)p;
            float4 q1 = *(const float4*)(p + 4);
            float4 q2 = *(const float4*)(p + 8);
            float  q3 = p[12];
            Wl[0][e] = (f16)q0.x;  Wl[1][e] = (f16)q0.y;  Wl[2][e] = (f16)q0.z;  Wl[3][e] = (f16)q0.w;
            Wl[4][e] = (f16)q1.x;  Wl[5][e] = (f16)q1.y;  Wl[6][e] = (f16)q1.z;  Wl[7][e] = (f16)q1.w;
            Wl[8][e] = (f16)q2.x;  Wl[9][e] = (f16)q2.y;  Wl[10][e] = (f16)q2.z; Wl[11][e] = (f16)q2.w;
            Wl[12][e] = (f16)q3;
        } else {
#pragma unroll
            for (int g = 0; g < 13; ++g) Wl[g][e] = (f16)0;
        }
    }
    __syncthreads();
    for (int t = tid; t < 48 * 13 * 4; t += 256) {
        int koct = t & 3; int q = t >> 2; int g = q % 13; int orel = q / 13;
        int o = o0 + orel;
        f16x8 v;
#pragma unroll
        for (int i = 0; i < 8; ++i) v[i] = Wl[g][orel * 32 + koct * 8 + i];
        int l = koct * 16 + (o & 15);
        int nt = o >> 4;
        *(f16x8*)&Wf1b[(((size_t)ks * 26 + c * 13 + g) * 6 + nt) * 512 + (size_t)l * 8] = v;
    }
}

__device__ __forceinline__ void conv1m_body(char* smem,
                                            const float* __restrict__ x,
                                            const float* __restrict__ b1,
                                            const f16* __restrict__ Wb1,
                                            f16* __restrict__ Tpre, int bid) {
    f16* tH = (f16*)smem;                       // 20,480 B
    f16* tL = (f16*)(smem + 20480);             // 20,480 B
    float* bl = (float*)(smem + 40960);         // 64 B
    const int b = bid >> 1, h2 = bid & 1;
    const int base = h2 * 14;
    const int tid = threadIdx.x;
    if (tid < 16) bl[tid] = (tid < 13) ? b1[tid] : 0.f;
    for (int i = tid; i < 640; i += 256) {
        f16x8 z = {};
        *(f16x8*)&tH[i * 16] = z; *(f16x8*)&tH[i * 16 + 8] = z;
        *(f16x8*)&tL[i * 16] = z; *(f16x8*)&tL[i * 16 + 8] = z;
    }
    __syncthreads();
    for (int s = tid; s < 560; s += 256) {
        int r = s / 28, ix = s % 28;
        int iy = base + r - 2;
        if ((unsigned)iy < 28u) {
            float v = x[(size_t)b * 784 + iy * 28 + ix];
            float s1, c1; __sincosf(v, &s1, &c1);
            float cg[5], sg[5];
            float ck = c1, sk = s1, ckm = 1.f, skm = 0.f;
#pragma unroll
            for (int g = 0; g < 5; ++g) {
                cg[g] = ck; sg[g] = sk;
                float cn = 2.f * c1 * ck - ckm, sn = 2.f * c1 * sk - skm;
                ckm = ck; ck = cn; skm = sk; sk = sn;
            }
            f16x8 hA, hB = {}, lA, lB = {};
#pragma unroll
            for (int g = 0; g < 5; ++g) {
                f16 h = (f16)cg[g]; hA[g] = h; lA[g] = (f16)(cg[g] - (float)h);
            }
#pragma unroll
            for (int g = 0; g < 3; ++g) {
                f16 h = (f16)sg[g]; hA[5 + g] = h; lA[5 + g] = (f16)(sg[g] - (float)h);
            }
#pragma unroll
            for (int g = 3; g < 5; ++g) {
                f16 h = (f16)sg[g]; hB[g - 3] = h; lB[g - 3] = (f16)(sg[g] - (float)h);
            }
            int pos = r * 32 + ix + 2;
            *(f16x8*)&tH[pos * 16] = hA; *(f16x8*)&tH[pos * 16 + 8] = hB;
            *(f16x8*)&tL[pos * 16] = lA; *(f16x8*)&tL[pos * 16 + 8] = lB;
        }
    }
    __syncthreads();

    const int l = tid & 63, w = tid >> 6;
    const int col = l & 15, g4 = l >> 4;
    const int tof = g4 >> 1, jh = g4 & 1;
    for (int pi = 0; pi < 2; ++pi) {
        int pl = w + 4 * pi;
        if (pl >= 7) break;
        f32x4 acc[4] = {};
#pragma unroll 1
        for (int pass = 0; pass < 3; ++pass) {
            const f16* pa = (pass == 1) ? tL : tH;
#pragma unroll
            for (int kc = 0; kc < 13; ++kc) {
                f16x8 bf = *(const f16x8*)&Wb1[((size_t)(pass * 13 + kc) * 64 + l) * 8];
                int tap = 2 * kc + tof;
                int ky = tap / 5, kx = tap - 5 * ky;
#pragma unroll
                for (int yy = 0; yy < 2; ++yy)
#pragma unroll
                    for (int hh = 0; hh < 2; ++hh) {
                        int pos = (2 * pl + yy + ky) * 32 + hh * 14 + col + kx;
                        f16x8 a = *(const f16x8*)&pa[pos * 16 + jh * 8];
                        acc[yy * 2 + hh] = __builtin_amdgcn_mfma_f32_16x16x32_f16(a, bf, acc[yy * 2 + hh], 0, 0, 0);
                    }
            }
        }
        if (col < 13) {
            int gpy = h2 * 7 + pl;
#pragma unroll
            for (int hh = 0; hh < 2; ++hh)
#pragma unroll
                for (int jp = 0; jp < 2; ++jp) {
                    if (g4 == 3 && jp == 1) continue;
                    int px = hh * 7 + 2 * g4 + jp;
                    float m = fmaxf(fmaxf(acc[hh][2 * jp], acc[hh][2 * jp + 1]),
                                    fmaxf(acc[2 + hh][2 * jp], acc[2 + hh][2 * jp + 1]));
                    float hval = m + bl[col];
                    float s1, c1; __sincosf(hval, &s1, &c1);
                    f16x8 vc, vs;
                    float ck = c1, sk = s1, ckm = 1.f, skm = 0.f;
#pragma unroll
                    for (int g = 0; g < 8; ++g) {
                        vc[g] = (f16)ck; vs[g] = (f16)sk;
                        float cn = 2.f * c1 * ck - ckm, sn = 2.f * c1 * sk - skm;
                        ckm = ck; ck = cn; skm = sk; sk = sn;
                    }
                    int p = gpy * 14 + px;
                    *(f16x8*)&Tpre[((size_t)(b * 26 + col) * 196 + p) * 8] = vc;
                    *(f16x8*)&Tpre[((size_t)(b * 26 + 13 + col) * 196 + p) * 8] = vs;
                }
        }
    }
}

__global__ __launch_bounds__(256) void k_mega(const float* __restrict__ x,
                                              const float* __restrict__ b1,
                                              const float* __restrict__ w2,
                                              const float* __restrict__ wf1,
                                              const f16* __restrict__ Wb1,
                                              f16* __restrict__ Wb2,
                                              f16* __restrict__ Wf1b,
                                              f16* __restrict__ Tpre) {
    __shared__ __align__(16) char smem[41024];
    int bid = blockIdx.x;
    if (bid < 512)       conv1m_body(smem, x, b1, Wb1, Tpre, bid);
    else if (bid < 1065) prep_wb_body(w2, Wb2, bid - 512);
    else                 prep_wf_body(smem, wf1, Wf1b, bid - 1065);
}

// ------------------------------------------------------------------
// K2: conv2 merged-parity (round-23) + BATCHED A-LOADS: all 12-13
// ds_read_b128 per unit issued up front into registers (static-
// indexed av[]), then the 91-MFMA burst runs from regs — decouples
// ds_read latency from the MFMA stream at 2 waves/SIMD.
// ------------------------------------------------------------------
template<int PAR>
__device__ __forceinline__ void c2_unit(const f16* __restrict__ Tb,
                                        const f16* __restrict__ Wb2,
                                        f32x16* acc, int cg, int kx,
                                        int oct, int pyb, int px, int l) {
    constexpr int NT  = 7 - PAR;
    constexpr int NKP = 13 - PAR;
    f16x8 bf[NT];
#pragma unroll
    for (int t = 0; t < NT; ++t) {
        int ky = PAR + 2 * t;
        bf[t] = *(const f16x8*)&Wb2[(((size_t)(cg * 13 + ky) * 13 + kx) * 64 + l) * 8];
    }
    const int xx = px + kx;
    f16x8 av[NKP];
#pragma unroll
    for (int kp = 0; kp < NKP; ++kp) {
        const int yy = PAR + 2 * kp + pyb;
        av[kp] = *(const f16x8*)&Tb[(((yy * 2 + oct) * 32) + xx) * 8];
    }
    __builtin_amdgcn_s_setprio(1);
#pragma unroll
    for (int kp = 0; kp < NKP; ++kp) {
#pragma unroll
        for (int t = 0; t < NT; ++t) {
            const int mt = kp - t;
            if (mt >= 0 && mt <= 6)
                acc[mt] = __builtin_amdgcn_mfma_f32_32x32x16_f16(av[kp], bf[t], acc[mt], 0, 0, 0);
        }
    }
    __builtin_amdgcn_s_setprio(0);
}

__global__ __launch_bounds__(512, 1) void k_conv2m(const f16* __restrict__ Tpre,
                                                   const f16* __restrict__ Wb2,
                                                   const float* __restrict__ b2,
                                                   float* __restrict__ h2f) {
    __shared__ f16 Tl[2 * 1792 * 8];   // 57,344 B
    const int b = blockIdx.x;
    const int tid = threadIdx.x;
    const int l = tid & 63, w = tid >> 6;   // 8 waves
    const int oct = l >> 5;
    const int pyb = (l >> 4) & 1;
    const int px = l & 15;

    for (int pos = tid; pos < 2 * 1792; pos += 512) {
        int r = (pos >= 1792) ? pos - 1792 : pos;
        int yy2 = r >> 5, xx = r & 31;
        int yy = yy2 >> 1;
        if (yy < 6 || yy >= 20 || xx < 6 || xx >= 20) {
            f16x8 z = {};
            *(f16x8*)&Tl[pos * 8] = z;
        }
    }

    auto ldT = [&](int cg, int j) -> f16x8 {
        int oc = (j >= 196), p = j - oc * 196;
        return *(const f16x8*)&Tpre[((size_t)(b * 26 + 2 * cg + oc) * 196 + p) * 8];
    };
    auto stT = [&](int buf, int j, f16x8 v) {
        int oc = (j >= 196), p = j - oc * 196;
        int y = p / 14, xp = p - y * 14;
        *(f16x8*)&Tl[(buf * 1792 + ((y + 6) * 2 + oc) * 32 + xp + 6) * 8] = v;
    };

    f16x8 pa, pb;
    if (tid < 392) { pa = ldT(0, tid); pb = ldT(1, tid); }

    f32x16 acc[7] = {};

    for (int cgp = 0; cgp < 13; cgp += 2) {
        const bool hasB = (cgp + 1 < 13);
        if (cgp) __syncthreads();            // prior phase MFMA reads done
        if (tid < 392) {
            stT(0, tid, pa);
            if (hasB) stT(1, tid, pb);
        }
        __syncthreads();
        if (tid < 392 && cgp + 2 < 13) {
            pa = ldT(cgp + 2, tid);
            if (cgp + 3 < 13) pb = ldT(cgp + 3, tid);
        }

        // units: uu = s*26 + par*13 + kx  (52 if hasB else 26)
        const int nu = hasB ? 52 : 26;
        const int res = (w + cgp) & 7;       // rotate ownership per phase
        for (int uu = res; uu < nu; uu += 8) {
            int s = (uu >= 26) ? 1 : 0;
            int r = uu - s * 26;
            int par = (r >= 13) ? 1 : 0;
            int kx = r - par * 13;
            int cg = cgp + s;
            const f16* Tb = &Tl[s * 1792 * 8];
            if (par == 0) c2_unit<0>(Tb, Wb2, acc, cg, kx, oct, pyb, px, l);
            else          c2_unit<1>(Tb, Wb2, acc, cg, kx, oct, pyb, px, l);
        }
    }

    // 8-wave reduction: waves 0-3 -> R0, waves 4-7 -> R1 (4 phases)
    __syncthreads();
    float* R0 = (float*)Tl;
    float* R1 = R0 + 7168;
    float* Rw = (w < 4) ? R0 : R1;
    const int wph = w & 3;
    for (int ph = 0; ph < 4; ++ph) {
        if (wph == ph) {
#pragma unroll
            for (int mt = 0; mt < 7; ++mt)
#pragma unroll
                for (int reg = 0; reg < 16; ++reg) {
                    int row = (reg & 3) + 8 * (reg >> 2) + 4 * oct;
                    int idx = (mt * 32 + row) * 32 + (l & 31);
                    float v = acc[mt][reg];
                    if (ph) v += Rw[idx];
                    Rw[idx] = v;
                }
        }
        __syncthreads();
    }

    // pool 2x2 + bias -> h2f
    for (int idx = tid; idx < 1029; idx += 512) {
        int o = idx % 21; int r = idx / 21; int px2 = r % 7; int py = r / 7;
        float mx = -1e30f;
#pragma unroll
        for (int sy = 0; sy < 2; ++sy)
#pragma unroll
            for (int sx = 0; sx < 2; ++sx) {
                int py2 = 2 * py + sy, pxx = 2 * px2 + sx;
                int mt = py2 >> 1, rr = (py2 & 1) * 16 + pxx;
                int ii = (mt * 32 + rr) * 32 + o;
                mx = fmaxf(mx, R0[ii] + R1[ii]);
            }
        h2f[(size_t)b * 1029 + o * 49 + py * 7 + px2] = mx + b2[o];
    }
}

// ------------------------------------------------------------------
// K4: fk1 via MFMA (b64 staging).
// ------------------------------------------------------------------
__global__ __launch_bounds__(256) void k_fk1m(const float* __restrict__ h2f,
                                              const f16* __restrict__ Wf1b,
                                              float* __restrict__ P3) {
    __shared__ f16 A[26 * 32 * 32];
    const int bid = blockIdx.x;
    const int mt8 = bid / NCH, ks = bid % NCH;
    const int m0 = mt8 * 32, d0 = ks * 32;
    const int tid = threadIdx.x;
    {
        const int m = tid >> 3, dq = tid & 7;
        float c1v[4], ck[4], sk[4], ckm[4], skm[4];
        bool valid[4];
#pragma unroll
        for (int j = 0; j < 4; ++j) {
            int d = d0 + dq * 4 + j;
            valid[j] = d < 1029;
            float h = valid[j] ? h2f[(size_t)(m0 + m) * 1029 + d] : 0.f;
            float s1, c1; __sincosf(h, &s1, &c1);
            c1v[j] = c1;
            ck[j] = c1; sk[j] = s1; ckm[j] = 1.f; skm[j] = 0.f;
        }
#pragma unroll
        for (int g = 0; g < 13; ++g) {
            f16x4 vc, vs;
#pragma unroll
            for (int j = 0; j < 4; ++j) {
                vc[j] = valid[j] ? (f16)ck[j] : (f16)0;
                vs[j] = valid[j] ? (f16)sk[j] : (f16)0;
                float cn = 2.f * c1v[j] * ck[j] - ckm[j];
                float sn = 2.f * c1v[j] * sk[j] - skm[j];
                ckm[j] = ck[j]; ck[j] = cn; skm[j] = sk[j]; sk[j] = sn;
            }
            *(f16x4*)&A[g * 1024 + m * 32 + dq * 4] = vc;
            *(f16x4*)&A[(13 + g) * 1024 + m * 32 + dq * 4] = vs;
        }
    }
    __syncthreads();
    const int w = tid >> 6, l = tid & 63;
    const int mt = w >> 1, ntg = (w & 1) * 3;
    f32x4 acc[3] = {};
    for (int kstep = 0; kstep < 26; ++kstep) {
        f16x8 a = *(const f16x8*)&A[kstep * 1024 + (mt * 16 + (l & 15)) * 32 + (l >> 4) * 8];
#pragma unroll
        for (int j = 0; j < 3; ++j) {
            f16x8 bv = *(const f16x8*)&Wf1b[((((size_t)ks * 26 + kstep) * 6 + ntg + j) * 64 + l) * 8];
            acc[j] = __builtin_amdgcn_mfma_f32_16x16x32_f16(a, bv, acc[j], 0, 0, 0);
        }
    }
    const int o_base = (l & 15);
#pragma unroll
    for (int j = 0; j < 3; ++j) {
        int o = (ntg + j) * 16 + o_base;
        if (o < 89) {
#pragma unroll
            for (int jj = 0; jj < 4; ++jj) {
                int m = m0 + mt * 16 + (l >> 4) * 4 + jj;
                P3[((size_t)ks * 256 + m) * 89 + o] = acc[j][jj];
            }
        }
    }
}

// ------------------------------------------------------------------
// K5: reduce 33 fk1 partials + bias -> trig(G=8) -> fk2 -> f32 out
// ------------------------------------------------------------------
__global__ __launch_bounds__(128) void k_fk2(const float* __restrict__ P3,
                                             const float* __restrict__ bias1,
                                             const float* __restrict__ wf2,
                                             const float* __restrict__ bias2,
                                             float* __restrict__ out) {
    __shared__ float2 tcs2[89][8];
    __shared__ float part[80];
    int b = blockIdx.x, tid = threadIdx.x;
    if (tid < 89) {
        float v = bias1[tid];
        for (int ks = 0; ks < NCH; ++ks)
            v += P3[((size_t)ks * 256 + b) * 89 + tid];
#pragma unroll
        for (int g = 0; g < 8; ++g) {
            float s, c; __sincosf(v * (float)(g + 1), &s, &c);
            tcs2[tid][g] = make_float2(c, s);
        }
    }
    __syncthreads();
    if (tid < 80) {
        int o = tid >> 3, g = tid & 7;
        float s = 0.f;
        for (int d = 0; d < 89; ++d) {
            float2 tv = tcs2[d][g];
            s = fmaf(tv.x, wf2[((size_t)o * 89 + d) * 8 + g],
                fmaf(tv.y, wf2[7120 + ((size_t)o * 89 + d) * 8 + g], s));
        }
        part[tid] = s;
    }
    __syncthreads();
    if (tid < 10) {
        float v = bias2[tid];
#pragma unroll
        for (int g = 0; g < 8; ++g) v += part[tid * 8 + g];
        out[b * 10 + tid] = v;
    }
}

extern "C" void kernel_launch(void* const* d_in, const int* in_sizes, int n_in,
                              void* d_out, int out_size, void* d_ws, size_t ws_size,
                              hipStream_t stream) {
    const float* x   = (const float*)d_in[0];
    const float* w1  = (const float*)d_in[1];
    const float* b1  = (const float*)d_in[2];
    const float* w2  = (const float*)d_in[3];
    const float* b2  = (const float*)d_in[4];
    const float* wf1 = (const float*)d_in[5];
    const float* bf1 = (const float*)d_in[6];
    const float* wf2 = (const float*)d_in[7];
    const float* bf2v = (const float*)d_in[8];

    char* ws  = (char*)d_ws;
    f16*   Tpre = (f16*)(ws + TP_OFF);
    f16*   Wb2  = (f16*)(ws + WB_OFF);
    f16*   Wf1b = (f16*)(ws + WF_OFF);
    f16*   Wb1  = (f16*)(ws + W1_OFF);
    float* h2f  = (float*)(ws + H2_OFF);
    float* P3   = (float*)(ws + P3_OFF);

    k_prep_w1<<<10, 256, 0, stream>>>(w1, Wb1);
    k_mega<<<1197, 256, 0, stream>>>(x, b1, w2, wf1, Wb1, Wb2, Wf1b, Tpre);
    k_conv2m<<<256, 512, 0, stream>>>(Tpre, Wb2, b2, h2f);
    k_fk1m<<<8 * NCH, 256, 0, stream>>>(h2f, Wf1b, P3);
    k_fk2<<<256, 128, 0, stream>>>(P3, bf1, wf2, bf2v, (float*)d_out);
}

// Round 25
// 163.006 us; speedup vs baseline: 1.0264x; 1.0264x over previous
//
#include <hip/hip_runtime.h>
#include <hip/hip_bf16.h>

typedef _Float16 f16;
typedef f16  f16x4 __attribute__((ext_vector_type(4)));
typedef f16  f16x8 __attribute__((ext_vector_type(8)));
typedef float f32x4 __attribute__((ext_vector_type(4)));
typedef float f32x16 __attribute__((ext_vector_type(16)));

// ---------------- workspace layout ----------------
// Tpre : [256][26(c,i)][196p][8g] f16
// Wb2  : [13cg][13ky][13kx][64l][8] f16
// Wf1b : [33ks][26kstep][6nt][64l][8] f16
// Wb1  : [39q][64l][8] f16
// h2f  : [256][1029] f32
// P3   : [33][256][89] f32
static constexpr size_t TP_OFF = 0;
static constexpr size_t TP_BYTES = (size_t)256 * 26 * 196 * 8 * 2;        // 20,873,216
static constexpr size_t WB_OFF = TP_OFF + TP_BYTES;
static constexpr size_t WB_BYTES = (size_t)2197 * 64 * 8 * 2;             // 2,249,728
static constexpr size_t WF_OFF = WB_OFF + WB_BYTES;
static constexpr size_t WF_BYTES = (size_t)33 * 26 * 6 * 64 * 8 * 2;      // 5,271,552
static constexpr size_t W1_OFF = WF_OFF + WF_BYTES;
static constexpr size_t W1_BYTES = (size_t)39 * 64 * 8 * 2;               // 39,936
static constexpr size_t H2_OFF = W1_OFF + ((W1_BYTES + 255) & ~size_t(255));
static constexpr size_t H2_BYTES = (size_t)256 * 1029 * 4;                // 1,053,696
static constexpr size_t P3_OFF = H2_OFF + H2_BYTES;

static constexpr int NCH = 33;

// ------------------------------------------------------------------
// K0: prep_w1 standalone (tiny) — precedes k_mega's conv1m blocks.
// ------------------------------------------------------------------
__global__ __launch_bounds__(256) void k_prep_w1(const float* __restrict__ w1,
                                                 f16* __restrict__ Wb1) {
    int idx = blockIdx.x * 256 + threadIdx.x;
    if (idx >= 39 * 64) return;
    int l = idx & 63; int q = idx >> 6;
    int pass = q / 13, kc = q % 13;
    int o = l & 15;
    f16x8 v;
#pragma unroll
    for (int i = 0; i < 8; ++i) {
        int kk = (l >> 4) * 8 + i;
        int tap = 2 * kc + (kk >> 4);
        int j = kk & 15;
        f16 out = (f16)0;
        if (tap < 25 && j < 10 && o < 13) {
            int c = j / 5, g = j % 5;
            int ky = tap / 5, kx = tap - 5 * ky;
            float wv = w1[c * 1625 + o * 125 + ky * 25 + kx * 5 + g];
            f16 hi = (f16)wv;
            out = (pass == 2) ? (f16)(wv - (float)hi) : hi;
        }
        v[i] = out;
    }
    *(f16x8*)&Wb1[(size_t)idx * 8] = v;
}

// ------------------------------------------------------------------
// Mega-kernel bodies: conv1m (512) + prep_wb (553) + prep_wf (132).
// ------------------------------------------------------------------
__device__ __forceinline__ void prep_wb_body(const float* __restrict__ w2,
                                             f16* __restrict__ Wb2, int bid) {
    int idx = bid * 256 + threadIdx.x;   // 2197*64 = 140,608
    if (idx >= 2197 * 64) return;
    int l = idx & 63; int frag = idx >> 6;
    int kx = frag % 13; int t2 = frag / 13;
    int ky = t2 % 13; int cg = t2 / 13;
    int o = l & 31;
    f16x8 v;
    int ch0 = cg * 16 + (l >> 5) * 8;
    int rr0 = ch0 % 104;
    if (o >= 21) {
        f16x8 z = {};
        v = z;
    } else if (rr0 <= 96) {
        int c2 = ch0 / 104, ii = rr0 >> 3;
        const float* src = &w2[(size_t)(c2 * 21 + o) * 17576 + ii * 1352 + ky * 104 + kx * 8];
        float4 a0 = *(const float4*)src;
        float4 a1 = *(const float4*)(src + 4);
        v[0] = (f16)a0.x; v[1] = (f16)a0.y; v[2] = (f16)a0.z; v[3] = (f16)a0.w;
        v[4] = (f16)a1.x; v[5] = (f16)a1.y; v[6] = (f16)a1.z; v[7] = (f16)a1.w;
    } else {
#pragma unroll
        for (int i = 0; i < 8; ++i) {
            int ch = ch0 + i;
            int c2 = ch / 104, rr = ch % 104, ii = rr >> 3, gg = rr & 7;
            v[i] = (f16)w2[(size_t)(c2 * 21 + o) * 17576 + ii * 1352 + ky * 104 + kx * 8 + gg];
        }
    }
    *(f16x8*)&Wb2[(size_t)idx * 8] = v;
}

__device__ __forceinline__ void prep_wf_body(char* smem,
                                             const float* __restrict__ wf1,
                                             f16* __restrict__ Wf1b, int sub) {
    f16 (*Wl)[48 * 32] = (f16(*)[48 * 32])smem;   // [13][1536] = 39,936 B
    int oseg = sub & 1, c = (sub >> 1) & 1, ks = sub >> 2;
    int o0 = oseg * 48;
    int tid = threadIdx.x;
    for (int e = tid; e < 48 * 32; e += 256) {
        int orel = e >> 5, dl = e & 31;
        int o = o0 + orel, d = ks * 32 + dl;
        if (o < 89 && d < 1029) {
            const float* p = wf1 + ((size_t)(c * 89 + o) * 1029 + d) * 13;
            float4 q0 = *(const float4*)p;
            float4 q1 = *(const float4*)(p + 4);
            float4 q2 = *(const float4*)(p + 8);
            float  q3 = p[12];
            Wl[0][e] = (f16)q0.x;  Wl[1][e] = (f16)q0.y;  Wl[2][e] = (f16)q0.z;  Wl[3][e] = (f16)q0.w;
            Wl[4][e] = (f16)q1.x;  Wl[5][e] = (f16)q1.y;  Wl[6][e] = (f16)q1.z;  Wl[7][e] = (f16)q1.w;
            Wl[8][e] = (f16)q2.x;  Wl[9][e] = (f16)q2.y;  Wl[10][e] = (f16)q2.z; Wl[11][e] = (f16)q2.w;
            Wl[12][e] = (f16)q3;
        } else {
#pragma unroll
            for (int g = 0; g < 13; ++g) Wl[g][e] = (f16)0;
        }
    }
    __syncthreads();
    for (int t = tid; t < 48 * 13 * 4; t += 256) {
        int koct = t & 3; int q = t >> 2; int g = q % 13; int orel = q / 13;
        int o = o0 + orel;
        f16x8 v;
#pragma unroll
        for (int i = 0; i < 8; ++i) v[i] = Wl[g][orel * 32 + koct * 8 + i];
        int l = koct * 16 + (o & 15);
        int nt = o >> 4;
        *(f16x8*)&Wf1b[(((size_t)ks * 26 + c * 13 + g) * 6 + nt) * 512 + (size_t)l * 8] = v;
    }
}

__device__ __forceinline__ void conv1m_body(char* smem,
                                            const float* __restrict__ x,
                                            const float* __restrict__ b1,
                                            const f16* __restrict__ Wb1,
                                            f16* __restrict__ Tpre, int bid) {
    f16* tH = (f16*)smem;                       // 20,480 B
    f16* tL = (f16*)(smem + 20480);             // 20,480 B
    float* bl = (float*)(smem + 40960);         // 64 B
    const int b = bid >> 1, h2 = bid & 1;
    const int base = h2 * 14;
    const int tid = threadIdx.x;
    if (tid < 16) bl[tid] = (tid < 13) ? b1[tid] : 0.f;
    for (int i = tid; i < 640; i += 256) {
        f16x8 z = {};
        *(f16x8*)&tH[i * 16] = z; *(f16x8*)&tH[i * 16 + 8] = z;
        *(f16x8*)&tL[i * 16] = z; *(f16x8*)&tL[i * 16 + 8] = z;
    }
    __syncthreads();
    for (int s = tid; s < 560; s += 256) {
        int r = s / 28, ix = s % 28;
        int iy = base + r - 2;
        if ((unsigned)iy < 28u) {
            float v = x[(size_t)b * 784 + iy * 28 + ix];
            float s1, c1; __sincosf(v, &s1, &c1);
            float cg[5], sg[5];
            float ck = c1, sk = s1, ckm = 1.f, skm = 0.f;
#pragma unroll
            for (int g = 0; g < 5; ++g) {
                cg[g] = ck; sg[g] = sk;
                float cn = 2.f * c1 * ck - ckm, sn = 2.f * c1 * sk - skm;
                ckm = ck; ck = cn; skm = sk; sk = sn;
            }
            f16x8 hA, hB = {}, lA, lB = {};
#pragma unroll
            for (int g = 0; g < 5; ++g) {
                f16 h = (f16)cg[g]; hA[g] = h; lA[g] = (f16)(cg[g] - (float)h);
            }
#pragma unroll
            for (int g = 0; g < 3; ++g) {
                f16 h = (f16)sg[g]; hA[5 + g] = h; lA[5 + g] = (f16)(sg[g] - (float)h);
            }
#pragma unroll
            for (int g = 3; g < 5; ++g) {
                f16 h = (f16)sg[g]; hB[g - 3] = h; lB[g - 3] = (f16)(sg[g] - (float)h);
            }
            int pos = r * 32 + ix + 2;
            *(f16x8*)&tH[pos * 16] = hA; *(f16x8*)&tH[pos * 16 + 8] = hB;
            *(f16x8*)&tL[pos * 16] = lA; *(f16x8*)&tL[pos * 16 + 8] = lB;
        }
    }
    __syncthreads();

    const int l = tid & 63, w = tid >> 6;
    const int col = l & 15, g4 = l >> 4;
    const int tof = g4 >> 1, jh = g4 & 1;
    for (int pi = 0; pi < 2; ++pi) {
        int pl = w + 4 * pi;
        if (pl >= 7) break;
        f32x4 acc[4] = {};
#pragma unroll 1
        for (int pass = 0; pass < 3; ++pass) {
            const f16* pa = (pass == 1) ? tL : tH;
#pragma unroll
            for (int kc = 0; kc < 13; ++kc) {
                f16x8 bf = *(const f16x8*)&Wb1[((size_t)(pass * 13 + kc) * 64 + l) * 8];
                int tap = 2 * kc + tof;
                int ky = tap / 5, kx = tap - 5 * ky;
#pragma unroll
                for (int yy = 0; yy < 2; ++yy)
#pragma unroll
                    for (int hh = 0; hh < 2; ++hh) {
                        int pos = (2 * pl + yy + ky) * 32 + hh * 14 + col + kx;
                        f16x8 a = *(const f16x8*)&pa[pos * 16 + jh * 8];
                        acc[yy * 2 + hh] = __builtin_amdgcn_mfma_f32_16x16x32_f16(a, bf, acc[yy * 2 + hh], 0, 0, 0);
                    }
            }
        }
        if (col < 13) {
            int gpy = h2 * 7 + pl;
#pragma unroll
            for (int hh = 0; hh < 2; ++hh)
#pragma unroll
                for (int jp = 0; jp < 2; ++jp) {
                    if (g4 == 3 && jp == 1) continue;
                    int px = hh * 7 + 2 * g4 + jp;
                    float m = fmaxf(fmaxf(acc[hh][2 * jp], acc[hh][2 * jp + 1]),
                                    fmaxf(acc[2 + hh][2 * jp], acc[2 + hh][2 * jp + 1]));
                    float hval = m + bl[col];
                    float s1, c1; __sincosf(hval, &s1, &c1);
                    f16x8 vc, vs;
                    float ck = c1, sk = s1, ckm = 1.f, skm = 0.f;
#pragma unroll
                    for (int g = 0; g < 8; ++g) {
                        vc[g] = (f16)ck; vs[g] = (f16)sk;
                        float cn = 2.f * c1 * ck - ckm, sn = 2.f * c1 * sk - skm;
                        ckm = ck; ck = cn; skm = sk; sk = sn;
                    }
                    int p = gpy * 14 + px;
                    *(f16x8*)&Tpre[((size_t)(b * 26 + col) * 196 + p) * 8] = vc;
                    *(f16x8*)&Tpre[((size_t)(b * 26 + 13 + col) * 196 + p) * 8] = vs;
                }
        }
    }
}

__global__ __launch_bounds__(256) void k_mega(const float* __restrict__ x,
                                              const float* __restrict__ b1,
                                              const float* __restrict__ w2,
                                              const float* __restrict__ wf1,
                                              const f16* __restrict__ Wb1,
                                              f16* __restrict__ Wb2,
                                              f16* __restrict__ Wf1b,
                                              f16* __restrict__ Tpre) {
    __shared__ __align__(16) char smem[41024];
    int bid = blockIdx.x;
    if (bid < 512)       conv1m_body(smem, x, b1, Wb1, Tpre, bid);
    else if (bid < 1065) prep_wb_body(w2, Wb2, bid - 512);
    else                 prep_wf_body(smem, wf1, Wf1b, bid - 1065);
}

// ------------------------------------------------------------------
// K2: conv2 merged-parity (round-23 form, best measured: 104 µs).
// Just-in-time A-loads (compiler-interleaved lgkmcnt schedule).
// ------------------------------------------------------------------
template<int PAR>
__device__ __forceinline__ void c2_unit(const f16* __restrict__ Tb,
                                        const f16* __restrict__ Wb2,
                                        f32x16* acc, int cg, int kx,
                                        int oct, int pyb, int px, int l) {
    constexpr int NT = 7 - PAR;
    f16x8 bf[NT];
#pragma unroll
    for (int t = 0; t < NT; ++t) {
        int ky = PAR + 2 * t;
        bf[t] = *(const f16x8*)&Wb2[(((size_t)(cg * 13 + ky) * 13 + kx) * 64 + l) * 8];
    }
    const int xx = px + kx;
    __builtin_amdgcn_s_setprio(1);
#pragma unroll
    for (int kp = 0; kp < 13 - PAR; ++kp) {
        const int yy = PAR + 2 * kp + pyb;
        f16x8 a = *(const f16x8*)&Tb[(((yy * 2 + oct) * 32) + xx) * 8];
#pragma unroll
        for (int t = 0; t < NT; ++t) {
            const int mt = kp - t;
            if (mt >= 0 && mt <= 6)
                acc[mt] = __builtin_amdgcn_mfma_f32_32x32x16_f16(a, bf[t], acc[mt], 0, 0, 0);
        }
    }
    __builtin_amdgcn_s_setprio(0);
}

__global__ __launch_bounds__(512, 1) void k_conv2m(const f16* __restrict__ Tpre,
                                                   const f16* __restrict__ Wb2,
                                                   const float* __restrict__ b2,
                                                   float* __restrict__ h2f) {
    __shared__ f16 Tl[2 * 1792 * 8];   // 57,344 B
    const int b = blockIdx.x;
    const int tid = threadIdx.x;
    const int l = tid & 63, w = tid >> 6;   // 8 waves
    const int oct = l >> 5;
    const int pyb = (l >> 4) & 1;
    const int px = l & 15;

    // zero halo in both buffers (each = 1792 cells of 16B)
    for (int pos = tid; pos < 2 * 1792; pos += 512) {
        int r = (pos >= 1792) ? pos - 1792 : pos;
        int yy2 = r >> 5, xx = r & 31;
        int yy = yy2 >> 1;
        if (yy < 6 || yy >= 20 || xx < 6 || xx >= 20) {
            f16x8 z = {};
            *(f16x8*)&Tl[pos * 8] = z;
        }
    }

    auto ldT = [&](int cg, int j) -> f16x8 {
        int oc = (j >= 196), p = j - oc * 196;
        return *(const f16x8*)&Tpre[((size_t)(b * 26 + 2 * cg + oc) * 196 + p) * 8];
    };
    auto stT = [&](int buf, int j, f16x8 v) {
        int oc = (j >= 196), p = j - oc * 196;
        int y = p / 14, xp = p - y * 14;
        *(f16x8*)&Tl[(buf * 1792 + ((y + 6) * 2 + oc) * 32 + xp + 6) * 8] = v;
    };

    f16x8 pa, pb;
    if (tid < 392) { pa = ldT(0, tid); pb = ldT(1, tid); }

    f32x16 acc[7] = {};

    for (int cgp = 0; cgp < 13; cgp += 2) {
        const bool hasB = (cgp + 1 < 13);
        if (cgp) __syncthreads();            // prior phase MFMA reads done
        if (tid < 392) {
            stT(0, tid, pa);
            if (hasB) stT(1, tid, pb);
        }
        __syncthreads();
        if (tid < 392 && cgp + 2 < 13) {
            pa = ldT(cgp + 2, tid);
            if (cgp + 3 < 13) pb = ldT(cgp + 3, tid);
        }

        // units: uu = s*26 + par*13 + kx  (52 if hasB else 26)
        const int nu = hasB ? 52 : 26;
        const int res = (w + cgp) & 7;       // rotate ownership per phase
        for (int uu = res; uu < nu; uu += 8) {
            int s = (uu >= 26) ? 1 : 0;
            int r = uu - s * 26;
            int par = (r >= 13) ? 1 : 0;
            int kx = r - par * 13;
            int cg = cgp + s;
            const f16* Tb = &Tl[s * 1792 * 8];
            if (par == 0) c2_unit<0>(Tb, Wb2, acc, cg, kx, oct, pyb, px, l);
            else          c2_unit<1>(Tb, Wb2, acc, cg, kx, oct, pyb, px, l);
        }
    }

    // 8-wave reduction: waves 0-3 -> R0, waves 4-7 -> R1 (4 phases)
    __syncthreads();
    float* R0 = (float*)Tl;
    float* R1 = R0 + 7168;
    float* Rw = (w < 4) ? R0 : R1;
    const int wph = w & 3;
    for (int ph = 0; ph < 4; ++ph) {
        if (wph == ph) {
#pragma unroll
            for (int mt = 0; mt < 7; ++mt)
#pragma unroll
                for (int reg = 0; reg < 16; ++reg) {
                    int row = (reg & 3) + 8 * (reg >> 2) + 4 * oct;
                    int idx = (mt * 32 + row) * 32 + (l & 31);
                    float v = acc[mt][reg];
                    if (ph) v += Rw[idx];
                    Rw[idx] = v;
                }
        }
        __syncthreads();
    }

    // pool 2x2 + bias -> h2f
    for (int idx = tid; idx < 1029; idx += 512) {
        int o = idx % 21; int r = idx / 21; int px2 = r % 7; int py = r / 7;
        float mx = -1e30f;
#pragma unroll
        for (int sy = 0; sy < 2; ++sy)
#pragma unroll
            for (int sx = 0; sx < 2; ++sx) {
                int py2 = 2 * py + sy, pxx = 2 * px2 + sx;
                int mt = py2 >> 1, rr = (py2 & 1) * 16 + pxx;
                int ii = (mt * 32 + rr) * 32 + o;
                mx = fmaxf(mx, R0[ii] + R1[ii]);
            }
        h2f[(size_t)b * 1029 + o * 49 + py * 7 + px2] = mx + b2[o];
    }
}

// ------------------------------------------------------------------
// K4: fk1 via MFMA (b64 staging).
// ------------------------------------------------------------------
__global__ __launch_bounds__(256) void k_fk1m(const float* __restrict__ h2f,
                                              const f16* __restrict__ Wf1b,
                                              float* __restrict__ P3) {
    __shared__ f16 A[26 * 32 * 32];
    const int bid = blockIdx.x;
    const int mt8 = bid / NCH, ks = bid % NCH;
    const int m0 = mt8 * 32, d0 = ks * 32;
    const int tid = threadIdx.x;
    {
        const int m = tid >> 3, dq = tid & 7;
        float c1v[4], ck[4], sk[4], ckm[4], skm[4];
        bool valid[4];
#pragma unroll
        for (int j = 0; j < 4; ++j) {
            int d = d0 + dq * 4 + j;
            valid[j] = d < 1029;
            float h = valid[j] ? h2f[(size_t)(m0 + m) * 1029 + d] : 0.f;
            float s1, c1; __sincosf(h, &s1, &c1);
            c1v[j] = c1;
            ck[j] = c1; sk[j] = s1; ckm[j] = 1.f; skm[j] = 0.f;
        }
#pragma unroll
        for (int g = 0; g < 13; ++g) {
            f16x4 vc, vs;
#pragma unroll
            for (int j = 0; j < 4; ++j) {
                vc[j] = valid[j] ? (f16)ck[j] : (f16)0;
                vs[j] = valid[j] ? (f16)sk[j] : (f16)0;
                float cn = 2.f * c1v[j] * ck[j] - ckm[j];
                float sn = 2.f * c1v[j] * sk[j] - skm[j];
                ckm[j] = ck[j]; ck[j] = cn; skm[j] = sk[j]; sk[j] = sn;
            }
            *(f16x4*)&A[g * 1024 + m * 32 + dq * 4] = vc;
            *(f16x4*)&A[(13 + g) * 1024 + m * 32 + dq * 4] = vs;
        }
    }
    __syncthreads();
    const int w = tid >> 6, l = tid & 63;
    const int mt = w >> 1, ntg = (w & 1) * 3;
    f32x4 acc[3] = {};
    for (int kstep = 0; kstep < 26; ++kstep) {
        f16x8 a = *(const f16x8*)&A[kstep * 1024 + (mt * 16 + (l & 15)) * 32 + (l >> 4) * 8];
#pragma unroll
        for (int j = 0; j < 3; ++j) {
            f16x8 bv = *(const f16x8*)&Wf1b[((((size_t)ks * 26 + kstep) * 6 + ntg + j) * 64 + l) * 8];
            acc[j] = __builtin_amdgcn_mfma_f32_16x16x32_f16(a, bv, acc[j], 0, 0, 0);
        }
    }
    const int o_base = (l & 15);
#pragma unroll
    for (int j = 0; j < 3; ++j) {
        int o = (ntg + j) * 16 + o_base;
        if (o < 89) {
#pragma unroll
            for (int jj = 0; jj < 4; ++jj) {
                int m = m0 + mt * 16 + (l >> 4) * 4 + jj;
                P3[((size_t)ks * 256 + m) * 89 + o] = acc[j][jj];
            }
        }
    }
}

// ------------------------------------------------------------------
// K5: reduce 33 fk1 partials + bias -> trig(G=8) -> fk2 -> f32 out
// ------------------------------------------------------------------
__global__ __launch_bounds__(128) void k_fk2(const float* __restrict__ P3,
                                             const float* __restrict__ bias1,
                                             const float* __restrict__ wf2,
                                             const float* __restrict__ bias2,
                                             float* __restrict__ out) {
    __shared__ float2 tcs2[89][8];
    __shared__ float part[80];
    int b = blockIdx.x, tid = threadIdx.x;
    if (tid < 89) {
        float v = bias1[tid];
        for (int ks = 0; ks < NCH; ++ks)
            v += P3[((size_t)ks * 256 + b) * 89 + tid];
#pragma unroll
        for (int g = 0; g < 8; ++g) {
            float s, c; __sincosf(v * (float)(g + 1), &s, &c);
            tcs2[tid][g] = make_float2(c, s);
        }
    }
    __syncthreads();
    if (tid < 80) {
        int o = tid >> 3, g = tid & 7;
        float s = 0.f;
        for (int d = 0; d < 89; ++d) {
            float2 tv = tcs2[d][g];
            s = fmaf(tv.x, wf2[((size_t)o * 89 + d) * 8 + g],
                fmaf(tv.y, wf2[7120 + ((size_t)o * 89 + d) * 8 + g], s));
        }
        part[tid] = s;
    }
    __syncthreads();
    if (tid < 10) {
        float v = bias2[tid];
#pragma unroll
        for (int g = 0; g < 8; ++g) v += part[tid * 8 + g];
        out[b * 10 + tid] = v;
    }
}

extern "C" void kernel_launch(void* const* d_in, const int* in_sizes, int n_in,
                              void* d_out, int out_size, void* d_ws, size_t ws_size,
                              hipStream_t stream) {
    const float* x   = (const float*)d_in[0];
    const float* w1  = (const float*)d_in[1];
    const float* b1  = (const float*)d_in[2];
    const float* w2  = (const float*)d_in[3];
    const float* b2  = (const float*)d_in[4];
    const float* wf1 = (const float*)d_in[5];
    const float* bf1 = (const float*)d_in[6];
    const float* wf2 = (const float*)d_in[7];
    const float* bf2v = (const float*)d_in[8];

    char* ws  = (char*)d_ws;
    f16*   Tpre = (f16*)(ws + TP_OFF);
    f16*   Wb2  = (f16*)(ws + WB_OFF);
    f16*   Wf1b = (f16*)(ws + WF_OFF);
    f16*   Wb1  = (f16*)(ws + W1_OFF);
    float* h2f  = (float*)(ws + H2_OFF);
    float* P3   = (float*)(ws + P3_OFF);

    k_prep_w1<<<10, 256, 0, stream>>>(w1, Wb1);
    k_mega<<<1197, 256, 0, stream>>>(x, b1, w2, wf1, Wb1, Wb2, Wf1b, Tpre);
    k_conv2m<<<256, 512, 0, stream>>>(Tpre, Wb2, b2, h2f);
    k_fk1m<<<8 * NCH, 256, 0, stream>>>(h2f, Wf1b, P3);
    k_fk2<<<256, 128, 0, stream>>>(P3, bf1, wf2, bf2v, (float*)d_out);
}